// Round 3
// baseline (476.260 us; speedup 1.0000x reference)
//
#include <hip/hip_runtime.h>
#include <math.h>

#define KDEG 64

struct ZTab {
    float z0r[KDEG], z0i[KDEG], z1r[KDEG], z1i[KDEG];
    float scale;
};

// === R8: REVERT to proven R1 (session best: 397 µs rocprof / 466 µs harness,
// absmax 0.0). This is the declared-roofline kernel. ===
//
// Roofline argument (R6/R7 post-mortem):
//  - Op count locked by bit-exactness: numpy complex64 rounding order = 16
//    separate rn f32 ops/iter × 64 iters = 1024 VALU slots/lane + ~70-slot
//    f64 hypotf epilogue. No fma / reassociation / Karatsuba / squared-compare
//    allowed — output is a hard 0/1 compare over 16.7M continuous margins;
//    any ULP deviation flips bits (absmax threshold requires 0).
//  - 2 cyc/slot (SIMD-32) × 2190 cyc/wave × 256 waves/SIMD @ ~1.57 GHz
//    (power-throttled dense-f32 clock, m07) = 357 µs busy. Measured busy =
//    397 µs × 91% VALUBusy = 361 µs. Model within 1%.
//  - pk-f32 is dead: R6 (hand asm) and R7 (compiler <2 x float>) both flipped
//    decision bits; and spec arithmetic (157.3 TF = scalar SIMD-32 rate ×
//    2.4 GHz exactly; no pk doubling on CDNA4, unlike MI300X's 81.7→163.4)
//    shows pk-f32 carries no extra throughput on gfx950 anyway.
//
// Load-path history (keep the scalar path!):
//  - R1/R8 (this): readfirstlane(row) -> coefficients via batched s_load
//    (SMEM pipe, broadcast through SGPRs). 397 µs, VALUBusy 91%.
//  - R2/R3: LDS-staged broadcast — flipped decision bits. DO NOT RETRY blind.
//  - R4: VMEM uniform-address broadcast — correct but 450 µs (addr VALU cost).
//  - R6/R7: packed f32 — WRONG RESULTS (and no throughput upside on CDNA4).
__global__ __launch_bounds__(256) void decoder_kernel(
    const float* __restrict__ xr, const float* __restrict__ xi,
    float* __restrict__ out, ZTab zt)
{
    const int lane = (int)(threadIdx.x & 63u);
    int row = ((int)blockIdx.x * (int)blockDim.x + (int)threadIdx.x) >> 6;
    // row is wave-uniform; scalarize so coefficient loads hit the SMEM pipe.
    row = __builtin_amdgcn_readfirstlane(row);

    const float* __restrict__ rr = xr + (size_t)row * (KDEG + 1);
    const float* __restrict__ ri = xi + (size_t)row * (KDEG + 1);

    const float z0r = zt.z0r[lane], z0i = zt.z0i[lane];
    const float z1r = zt.z1r[lane], z1i = zt.z1i[lane];

    // init = x[:, 0] broadcast
    float a0r = rr[0], a0i = ri[0];
    float a1r = a0r,  a1i = a0i;

#pragma unroll
    for (int i = 1; i <= KDEG; ++i) {
        const float cr = rr[i];
        const float ci = ri[i];
        // res = res*z + c, numpy complex64 op order: (ar*br - ai*bi), (ar*bi + ai*br)
        float t0r = __fadd_rn(__fsub_rn(__fmul_rn(a0r, z0r), __fmul_rn(a0i, z0i)), cr);
        float t0i = __fadd_rn(__fadd_rn(__fmul_rn(a0r, z0i), __fmul_rn(a0i, z0r)), ci);
        float t1r = __fadd_rn(__fsub_rn(__fmul_rn(a1r, z1r), __fmul_rn(a1i, z1i)), cr);
        float t1i = __fadd_rn(__fadd_rn(__fmul_rn(a1r, z1i), __fmul_rn(a1i, z1r)), ci);
        a0r = t0r; a0i = t0i;
        a1r = t1r; a1i = t1i;
    }

    // |res| matching numpy/glibc hypotf: (float)sqrt((double)a*a + (double)b*b)
    // (float->double squares exact; one double rounding on the sum; IEEE double
    //  sqrt; final round to float). Bit-exact requirement — do not replace.
    float h0 = (float)sqrt((double)a0r * (double)a0r + (double)a0i * (double)a0i);
    float h1 = (float)sqrt((double)a1r * (double)a1r + (double)a1i * (double)a1i);

    out[(size_t)row * KDEG + lane] = (__fmul_rn(zt.scale, h0) >= h1) ? 1.0f : 0.0f;
}

extern "C" void kernel_launch(void* const* d_in, const int* in_sizes, int n_in,
                              void* d_out, int out_size, void* d_ws, size_t ws_size,
                              hipStream_t stream)
{
    const float* xr = (const float*)d_in[0];
    const float* xi = (const float*)d_in[1];
    float* out = (float*)d_out;

    const int B = in_sizes[0] / (KDEG + 1);  // 262144

    // Host-side constant table, replicating numpy's float64 math exactly
    // (same glibc libm as the reference environment), then rounding to f32.
    ZTab zt;
    const double r = sqrt(1.0 + sin(M_PI / (double)KDEG));
    const double inv_r = 1.0 / r;
    for (int j = 0; j < KDEG; ++j) {
        double ang = (2.0 * M_PI) * (double)j / (double)KDEG;  // ((2π)*j)/K, numpy order
        double c = cos(ang), s = sin(ang);
        zt.z0r[j] = (float)(inv_r * c);
        zt.z0i[j] = (float)(inv_r * s);
        zt.z1r[j] = (float)(r * c);
        zt.z1i[j] = (float)(r * s);
    }
    zt.scale = (float)pow(r, (double)KDEG);

    // One wave per row, 4 rows per 256-thread block.
    const int rows_per_block = 4;
    const int grid = (B + rows_per_block - 1) / rows_per_block;
    decoder_kernel<<<grid, 256, 0, stream>>>(xr, xi, out, zt);
}